// Round 6
// baseline (103093.689 us; speedup 1.0000x reference)
//
#include <hip/hip_runtime.h>
#include <math.h>

#define Tt 512
#define Dd 768
#define Hh 512
#define Bb 32
#define G3 1536
#define HB (Hh*Bb)
#define NBLK 256
#define NTHR 512
#define NBAR (Tt*4)

// packed weight layout (floats, per block): [S1: 128kk*18row*4][S2: 128*8*4][S3: 128*10*4][S4: 128*2*4]
#define S1OFF 0
#define S2OFF 9216
#define S3OFF 13312
#define S4OFF 18432
#define WPB   19456

__device__ __forceinline__ float sigf(float x) { return 1.f / (1.f + expf(-x)); }

__device__ __forceinline__ float dot4f(const float4 w4, const float4 v) {
  return w4.x*v.x + w4.y*v.y + w4.z*v.z + w4.w*v.w;
}

// float index of state element (k,b) in [k/4][b][4] layout
__device__ __forceinline__ int sidx(int k, int b) { return ((k >> 2) * 32 + b) * 4 + (k & 3); }

__device__ __forceinline__ void dstore(float* p, float v) {
  __hip_atomic_store(p, v, __ATOMIC_RELAXED, __HIP_MEMORY_SCOPE_AGENT);
}
__device__ __forceinline__ void dstore_u(unsigned* p, unsigned v) {
  __hip_atomic_store(p, v, __ATOMIC_RELAXED, __HIP_MEMORY_SCOPE_AGENT);
}
__device__ __forceinline__ unsigned dload_u(const unsigned* p) {
  return __hip_atomic_load(p, __ATOMIC_RELAXED, __HIP_MEMORY_SCOPE_AGENT);
}

// ---- barrier (R2-proven shape): two-level fetch_add arrive, 16 replica release
// flags, ONE poller lane per block on its group's replica. Monotone targets. ----
__device__ __forceinline__ void bar_arrive(unsigned* bc1, unsigned* bc2, unsigned* gfl, unsigned n)
{
  __syncthreads();   // drains vmcnt(0): all block loads/stores complete before arrival
  if (threadIdx.x == 0) {
    const unsigned idx = n - 1u;
    const unsigned grp = (unsigned)(blockIdx.x >> 4);   // 16 groups x 16 blocks
    unsigned old = __hip_atomic_fetch_add(&bc1[(idx * 16u + grp) * 16u], 1u,
                        __ATOMIC_RELAXED, __HIP_MEMORY_SCOPE_AGENT);
    if (old == 15u) {
      unsigned o2 = __hip_atomic_fetch_add(&bc2[idx * 16u], 1u,
                        __ATOMIC_RELAXED, __HIP_MEMORY_SCOPE_AGENT);
      if (o2 == 15u) {
#pragma unroll
        for (int g = 0; g < 16; ++g) dstore_u(&gfl[g * 16], n);
      }
    }
  }
}

__device__ __forceinline__ void bar_wait(unsigned* gfl, unsigned n)
{
  if (threadIdx.x == 0) {
    const unsigned grp = (unsigned)(blockIdx.x >> 4);
    while (dload_u(&gfl[grp * 16]) < n) __builtin_amdgcn_s_sleep(2);
  }
  __syncthreads();
}

__device__ __forceinline__ void grid_barrier(unsigned* bc1, unsigned* bc2, unsigned* gfl, unsigned n)
{
  bar_arrive(bc1, bc2, gfl, n);
  bar_wait(gfl, n);
}

// ---------------- weight packing ----------------
__global__ __launch_bounds__(256) void pack_weights(
    const float* __restrict__ Whh0, const float* __restrict__ Wih,
    const float* __restrict__ Whh,  const float* __restrict__ mW1,
    const float* __restrict__ mW2,  float* __restrict__ Wp)
{
  const int blk = blockIdx.x, i0 = blk * 2;
  for (int idx = threadIdx.x; idx < WPB; idx += 256) {
    float v; int kk, w, c;
    if (idx < S2OFF) {
      int r = idx; kk = r / 72; int q = r % 72; w = q >> 2; c = q & 3;
      int k = kk * 4 + c, l = w / 6, rem = w % 6, g = rem >> 1, ii = rem & 1;
      int row = g * 512 + i0 + ii;
      v = (l == 0) ? Whh0[(size_t)row * 512 + k] : Whh[((size_t)(l - 1) * G3 + row) * 512 + k];
    } else if (idx < S3OFF) {
      int r = idx - S2OFF; kk = r / 32; int q = r % 32; w = q >> 2; c = q & 3;
      int k = kk * 4 + c;
      v = (w < 6) ? Wih[((size_t)(w >> 1) * 512 + i0 + (w & 1)) * 512 + k]
                  : mW1[(size_t)(i0 + (w - 6)) * 512 + k];
    } else if (idx < S4OFF) {
      int r = idx - S3OFF; kk = r / 40; int q = r % 40; w = q >> 2; c = q & 3;
      int k = kk * 4 + c;
      v = (w < 6) ? Wih[((size_t)G3 + (w >> 1) * 512 + i0 + (w & 1)) * 512 + k]
        : (w < 8) ? mW2[(size_t)(i0 + (w - 6)) * 512 + k]
                  : mW1[((size_t)512 + i0 + (w - 8)) * 512 + k];
    } else {
      int r = idx - S4OFF; kk = r / 8; int q = r % 8; w = q >> 2; c = q & 3;
      int k = kk * 4 + c;
      v = mW2[((size_t)512 + i0 + w) * 512 + k];
    }
    Wp[(size_t)blk * WPB + idx] = v;
  }
}

// ---------------- GI0 = x @ Wih0^T + bih0, t-tiled by 4, layout [t][j][b] ----------------
__global__ __launch_bounds__(256) void gi0_gemm(const float* __restrict__ x,
                                                const float* __restrict__ Wih0,
                                                const float* __restrict__ bih0,
                                                float* __restrict__ GI0)
{
  const int t0 = blockIdx.x * 4;
  const int j0 = blockIdx.y * 128;
  const int tid = threadIdx.x;
  const int b = tid & 31, u = tid >> 5;   // u in [0,8)

  __shared__ float xs[4][64][33];
  float acc[16][4];
#pragma unroll
  for (int jj = 0; jj < 16; jj++)
#pragma unroll
    for (int tt = 0; tt < 4; tt++) acc[jj][tt] = 0.f;

  for (int kbv = 0; kbv < Dd; kbv += 64) {
    __syncthreads();
    {
      int r = tid >> 1, half = tid & 1;
      int tt = r >> 5, bb = r & 31;
      const float* xp = x + ((size_t)bb * Tt + t0 + tt) * Dd + kbv + half * 32;
#pragma unroll
      for (int q = 0; q < 8; q++) {
        float4 v = *(const float4*)(xp + q * 4);
        int k = half * 32 + q * 4;
        xs[tt][k + 0][bb] = v.x; xs[tt][k + 1][bb] = v.y;
        xs[tt][k + 2][bb] = v.z; xs[tt][k + 3][bb] = v.w;
      }
    }
    __syncthreads();
    for (int kk4 = 0; kk4 < 16; kk4++) {
      const int k = kk4 * 4;
      float xv[4][4];
#pragma unroll
      for (int tt = 0; tt < 4; tt++)
#pragma unroll
        for (int q = 0; q < 4; q++) xv[tt][q] = xs[tt][k + q][b];
#pragma unroll
      for (int jj = 0; jj < 16; jj++) {
        const float* wp = Wih0 + (size_t)(j0 + u + 8 * jj) * Dd + kbv + k;
        float4 w4 = *(const float4*)wp;
#pragma unroll
        for (int tt = 0; tt < 4; tt++)
          acc[jj][tt] += w4.x*xv[tt][0] + w4.y*xv[tt][1] + w4.z*xv[tt][2] + w4.w*xv[tt][3];
      }
    }
  }
#pragma unroll
  for (int jj = 0; jj < 16; jj++) {
    int j = j0 + u + 8 * jj;
    float bj = bih0[j];
#pragma unroll
    for (int tt = 0; tt < 4; tt++)
      GI0[((size_t)(t0 + tt) * G3 + j) * 32 + b] = acc[jj][tt] + bj;
  }
}

// ---------------- persistent HRNN kernel ----------------
// Memory scheme = R2 (proven): c0 parity double-buffer, c1/c2/m0a/m1a in place.
// Total state ~384 KB -> permanently L2/MALL-hot. Plain cached reads, agent-scope
// write-through stores (empirically coherent: R2 passed bit-exact, FETCH 1.4 MB/step).
__global__ __launch_bounds__(NTHR, 1) void hrnn_persist(
    const float* __restrict__ Wp,
    const float* __restrict__ bhh0, const float* __restrict__ bih,
    const float* __restrict__ bhh,  const float* __restrict__ mb1,
    const float* __restrict__ mb2,  const float* __restrict__ mW3,
    const float* __restrict__ mb3,  const float* __restrict__ GI0,
    float* __restrict__ c0T, float* __restrict__ c1T, float* __restrict__ c2T,
    float* __restrict__ m0aT, float* __restrict__ m1aT,
    float* __restrict__ pacc,
    unsigned* __restrict__ bc1, unsigned* __restrict__ bc2, unsigned* __restrict__ gfl,
    float* __restrict__ out)
{
  __shared__ float red[8][576];
  __shared__ float s_gh[12][32];
  __shared__ float s_pre[6][32];
  __shared__ float s_gi[6][32];
  __shared__ float s_ab[7][32];    // a0,a1,a2,w10,w11,p0,p1
  __shared__ float s_mb[2][32];
  __shared__ float s_g0[6][32];    // GI0 prefetch: rows {i0,i0+1}+{0,512,1024}

  const int tid = threadIdx.x;
  const int b = tid & 31;
  const int u = tid >> 5;          // 0..15
  const int wv = tid >> 6;         // wave 0..7
  const int i0 = blockIdx.x * 2;
  const int pgrp = blockIdx.x & 31;   // pacc group: depth-8 atomic chains
  const float* wpk = Wp + (size_t)blockIdx.x * WPB;

  for (int t = 0; t < Tt; t++) {
    const int par = t & 1;
    float* c0n_w = c0T + (size_t)par * HB;
    const float* c0o_p = c0T + (size_t)(1 - par) * HB;

    // ---- prefetch old states + GI0 (issued BEFORE waiting on S4 of t-1) ----
    // c0old written S1(t-1), c1 written S2(t-1), c2 written S3(t-1): all barriers
    // this block has already passed. Loads drain at bar_arrive's syncthreads, so
    // no in-flight read can cross a later writer's barrier.
    const float4* c0v = (const float4*)c0o_p;
    const float4* c1v = (const float4*)c1T;
    const float4* c2v = (const float4*)c2T;
    float4 sv0[8], sv1[8], sv2[8];
#pragma unroll
    for (int j = 0; j < 8; j++) {
      int fi = (u * 8 + j) * 32 + b;
      sv0[j] = c0v[fi]; sv1[j] = c1v[fi]; sv2[j] = c2v[fi];
    }
    float v0e = 0.f, v1e = 0.f, v2e = 0.f;
    int sie = 0;
    if (tid < 192) {
      int rw = tid >> 5, b2 = tid & 31;
      int j = (rw >> 1) * 512 + i0 + (rw & 1);
      s_g0[rw][b2] = GI0[((size_t)t * G3 + j) * 32 + b2];
    }
    if (tid < 64) {
      int ii = tid >> 5, bb = tid & 31;
      sie = sidx(i0 + ii, bb);
      v0e = c0o_p[sie]; v1e = c1T[sie]; v2e = c2T[sie];
    }

    // ---- wait for S4 arrivals of step t-1 (p1 partials complete) ----
    if (t > 0) bar_wait(gfl, (unsigned)(4 * t));
    else __syncthreads();   // order s_g0 writes

    // ---- p-phase ----
    {
      const int pslot = (t + Tt - 1) & (Tt - 1);
      if (tid < 64) {
        int which = tid >> 5, b2 = tid & 31;
        const float* pp = pacc + ((size_t)pslot * 2 + which) * 1024;
        float s = mb3[which];
#pragma unroll
        for (int g = 0; g < 32; g++) s += pp[g * 32 + b2];
        s_ab[5 + which][b2] = sigf(s);
      }
      __syncthreads();
      if (tid < 32) {
        float p0 = s_ab[5][tid], p1 = s_ab[6][tid];
        float e0 = expf(1.f - p0), e1 = expf(p0 * (1.f - p1)), e2 = expf(p0 * p1);
        float inv = 1.f / (e0 + e1 + e2);
        s_ab[0][tid] = e0 * inv; s_ab[1][tid] = e1 * inv; s_ab[2][tid] = e2 * inv;
        float q0 = expf(1.f - p1), q1 = expf(p1);
        float qi = 1.f / (q0 + q1);
        s_ab[3][tid] = q0 * qi; s_ab[4][tid] = q1 * qi;
        if (t > 0 && blockIdx.x == NBLK - 1) {
          out[((size_t)tid * Tt + (t - 1)) * 2 + 0] = p0;
          out[((size_t)tid * Tt + (t - 1)) * 2 + 1] = p1;
        }
      }
      __syncthreads();
    }

    const float a0 = s_ab[0][b], a1 = s_ab[1][b], a2 = s_ab[2][b];
    const float w10 = s_ab[3][b], w11 = s_ab[4][b];

    // ---- S1: gh0/gh1/gh2 with inline h-mixing; cell0 ----
    {
      const float4* wb = (const float4*)(wpk + S1OFF) + (size_t)u * 8 * 18;
      float acc[18];
#pragma unroll
      for (int w = 0; w < 18; w++) acc[w] = 0.f;
#pragma unroll
      for (int j = 0; j < 8; j++) {
        float4 mh0, mh1, v2 = sv2[j];
        mh0.x = a0*sv0[j].x + a1*sv1[j].x + a2*v2.x;
        mh0.y = a0*sv0[j].y + a1*sv1[j].y + a2*v2.y;
        mh0.z = a0*sv0[j].z + a1*sv1[j].z + a2*v2.z;
        mh0.w = a0*sv0[j].w + a1*sv1[j].w + a2*v2.w;
        mh1.x = w10*sv1[j].x + w11*v2.x;  mh1.y = w10*sv1[j].y + w11*v2.y;
        mh1.z = w10*sv1[j].z + w11*v2.z;  mh1.w = w10*sv1[j].w + w11*v2.w;
#pragma unroll
        for (int w = 0; w < 18; w++) {
          float4 w4 = wb[j * 18 + w];
          acc[w] += dot4f(w4, (w < 6) ? mh0 : (w < 12) ? mh1 : v2);
        }
      }
#pragma unroll
      for (int w = 0; w < 18; w++) acc[w] += __shfl_xor(acc[w], 32, 64);
      if ((tid & 63) < 32) {
#pragma unroll
        for (int w = 0; w < 18; w++) red[wv][w * 32 + b] = acc[w];
      }
      __syncthreads();
      for (int o = tid; o < 18 * 32; o += NTHR) {
        float s = 0.f;
#pragma unroll
        for (int q = 0; q < 8; q++) s += red[q][o];
        int w = o >> 5, b2 = o & 31;
        int l = w / 6, rem = w % 6, g = rem >> 1, ii = rem & 1;
        int row = g * 512 + i0 + ii;
        if (l == 0) {
          s += bhh0[row];
          if (g < 2) s += s_g0[rem][b2];
          s_pre[rem][b2] = s;
        } else if (l == 1) {
          s_gh[rem][b2] = s + bhh[row];
        } else {
          s_gh[6 + rem][b2] = s + bhh[G3 + row];
        }
      }
      __syncthreads();
      if (tid < 64) {
        int ii = tid >> 5, bb = tid & 31;
        float r = sigf(s_pre[ii][bb]);
        float z = sigf(s_pre[2 + ii][bb]);
        float n = tanhf(s_g0[4 + ii][bb] + r * s_pre[4 + ii][bb]);
        float h0old = s_ab[0][bb] * v0e + s_ab[1][bb] * v1e + s_ab[2][bb] * v2e;
        dstore(&c0n_w[sie], (1.f - z) * n + z * h0old);
      }
    }
    grid_barrier(bc1, bc2, gfl, (unsigned)(4 * t + 1));

    // ---- S2: gi1 (over cell0) + m0a; cell1 ----
    {
      const float4* c0n = (const float4*)c0n_w;
      const float4* wb = (const float4*)(wpk + S2OFF) + (size_t)u * 8 * 8;
      float4 sv[8];
#pragma unroll
      for (int j = 0; j < 8; j++) sv[j] = c0n[(u * 8 + j) * 32 + b];
      float acc[8];
#pragma unroll
      for (int w = 0; w < 8; w++) acc[w] = 0.f;
#pragma unroll
      for (int j = 0; j < 8; j++) {
#pragma unroll
        for (int w = 0; w < 8; w++) acc[w] += dot4f(wb[j * 8 + w], sv[j]);
      }
#pragma unroll
      for (int w = 0; w < 8; w++) acc[w] += __shfl_xor(acc[w], 32, 64);
      if ((tid & 63) < 32) {
#pragma unroll
        for (int w = 0; w < 8; w++) red[wv][w * 32 + b] = acc[w];
      }
      __syncthreads();
      if (tid < 8 * 32) {
        float s = 0.f;
#pragma unroll
        for (int q = 0; q < 8; q++) s += red[q][tid];
        int w = tid >> 5, b2 = tid & 31;
        if (w < 6) {
          int row = (w >> 1) * 512 + i0 + (w & 1);
          s_gi[w][b2] = s + bih[row];
        } else {
          int col = i0 + (w - 6);
          dstore(&m0aT[sidx(col, b2)], fmaxf(s + mb1[col], 0.f));
        }
      }
      __syncthreads();
      if (tid < 64) {
        int ii = tid >> 5, bb = tid & 31;
        float r = sigf(s_gi[ii][bb] + s_gh[ii][bb]);
        float z = sigf(s_gi[2 + ii][bb] + s_gh[2 + ii][bb]);
        float n = tanhf(s_gi[4 + ii][bb] + r * s_gh[4 + ii][bb]);
        float h1old = s_ab[3][bb] * v1e + s_ab[4][bb] * v2e;
        dstore(&c1T[sie], (1.f - z) * n + z * h1old);
      }
    }
    grid_barrier(bc1, bc2, gfl, (unsigned)(4 * t + 2));

    // ---- S3: gi2 + m0b + m1a; cell2; p0 partials ----
    {
      const float4* c1n = (const float4*)c1T;
      const float4* m0a = (const float4*)m0aT;
      const float4* wb = (const float4*)(wpk + S3OFF) + (size_t)u * 8 * 10;
      float4 sv[8], sm[8];
#pragma unroll
      for (int j = 0; j < 8; j++) {
        int fi = (u * 8 + j) * 32 + b;
        sv[j] = c1n[fi]; sm[j] = m0a[fi];
      }
      float acc[10];
#pragma unroll
      for (int w = 0; w < 10; w++) acc[w] = 0.f;
#pragma unroll
      for (int j = 0; j < 8; j++) {
#pragma unroll
        for (int w = 0; w < 10; w++)
          acc[w] += dot4f(wb[j * 10 + w], (w == 6 || w == 7) ? sm[j] : sv[j]);
      }
#pragma unroll
      for (int w = 0; w < 10; w++) acc[w] += __shfl_xor(acc[w], 32, 64);
      if ((tid & 63) < 32) {
#pragma unroll
        for (int w = 0; w < 10; w++) red[wv][w * 32 + b] = acc[w];
      }
      __syncthreads();
      if (tid < 10 * 32) {
        float s = 0.f;
#pragma unroll
        for (int q = 0; q < 8; q++) s += red[q][tid];
        int w = tid >> 5, b2 = tid & 31;
        if (w < 6) {
          int row = (w >> 1) * 512 + i0 + (w & 1);
          s_gi[w][b2] = s + bih[G3 + row];
        } else if (w < 8) {
          s_mb[w - 6][b2] = fmaxf(s + mb2[i0 + (w - 6)], 0.f);
        } else {
          int col = i0 + (w - 8);
          dstore(&m1aT[sidx(col, b2)], fmaxf(s + mb1[512 + col], 0.f));
        }
      }
      __syncthreads();
      if (tid < 64) {
        int ii = tid >> 5, bb = tid & 31;
        float r = sigf(s_gi[ii][bb] + s_gh[6 + ii][bb]);
        float z = sigf(s_gi[2 + ii][bb] + s_gh[8 + ii][bb]);
        float n = tanhf(s_gi[4 + ii][bb] + r * s_gh[10 + ii][bb]);
        dstore(&c2T[sie], (1.f - z) * n + z * v2e);
      } else if (tid < 96) {
        int b2 = tid - 64;
        float part = mW3[i0] * s_mb[0][b2] + mW3[i0 + 1] * s_mb[1][b2];
        __hip_atomic_fetch_add(&pacc[((size_t)t * 2 + 0) * 1024 + pgrp * 32 + b2], part,
                               __ATOMIC_RELAXED, __HIP_MEMORY_SCOPE_AGENT);
      }
    }
    grid_barrier(bc1, bc2, gfl, (unsigned)(4 * t + 3));

    // ---- S4: m1b + p1 partials; arrive-only (wait folded into next p-phase) ----
    {
      const float4* m1a = (const float4*)m1aT;
      const float4* wb = (const float4*)(wpk + S4OFF) + (size_t)u * 8 * 2;
      float acc2[2] = {0.f, 0.f};
#pragma unroll
      for (int j = 0; j < 8; j++) {
        float4 vm = m1a[(u * 8 + j) * 32 + b];
        acc2[0] += dot4f(wb[j * 2 + 0], vm);
        acc2[1] += dot4f(wb[j * 2 + 1], vm);
      }
#pragma unroll
      for (int w = 0; w < 2; w++) acc2[w] += __shfl_xor(acc2[w], 32, 64);
      if ((tid & 63) < 32) {
        red[wv][b] = acc2[0]; red[wv][32 + b] = acc2[1];
      }
      __syncthreads();
      if (tid < 64) {
        float s = 0.f;
#pragma unroll
        for (int q = 0; q < 8; q++) s += red[q][tid];
        int w = tid >> 5, b2 = tid & 31;
        s_mb[w][b2] = fmaxf(s + mb2[512 + i0 + w], 0.f);
      }
      __syncthreads();
      if (tid >= 64 && tid < 96) {
        int b2 = tid - 64;
        float part = mW3[512 + i0] * s_mb[0][b2] + mW3[512 + i0 + 1] * s_mb[1][b2];
        __hip_atomic_fetch_add(&pacc[((size_t)t * 2 + 1) * 1024 + pgrp * 32 + b2], part,
                               __ATOMIC_RELAXED, __HIP_MEMORY_SCOPE_AGENT);
      }
    }
    bar_arrive(bc1, bc2, gfl, (unsigned)(4 * t + 4));
  }

  // ---- final output column t = T-1 (writer waits for last S4 completion) ----
  if (blockIdx.x == NBLK - 1) {
    bar_wait(gfl, (unsigned)(4 * Tt));
    if (tid < 64) {
      int which = tid >> 5, b2 = tid & 31;
      const float* pp = pacc + ((size_t)(Tt - 1) * 2 + which) * 1024;
      float s = mb3[which];
#pragma unroll
      for (int g = 0; g < 32; g++) s += pp[g * 32 + b2];
      out[((size_t)b2 * Tt + (Tt - 1)) * 2 + which] = sigf(s);
    }
  }
}

extern "C" void kernel_launch(void* const* d_in, const int* in_sizes, int n_in,
                              void* d_out, int out_size, void* d_ws, size_t ws_size,
                              hipStream_t stream)
{
  (void)in_sizes; (void)n_in; (void)out_size;
  const float* x    = (const float*)d_in[0];
  const float* Wih0 = (const float*)d_in[1];
  const float* Whh0 = (const float*)d_in[2];
  const float* bih0 = (const float*)d_in[3];
  const float* bhh0 = (const float*)d_in[4];
  const float* Wih  = (const float*)d_in[5];
  const float* Whh  = (const float*)d_in[6];
  const float* bih  = (const float*)d_in[7];
  const float* bhh  = (const float*)d_in[8];
  const float* mW1  = (const float*)d_in[9];
  const float* mb1  = (const float*)d_in[10];
  const float* mW2  = (const float*)d_in[11];
  const float* mb2  = (const float*)d_in[12];
  const float* mW3  = (const float*)d_in[13];
  const float* mb3  = (const float*)d_in[14];
  float* out = (float*)d_out;

  char* ws = (char*)d_ws;
  size_t off = 0;
  auto take = [&](size_t bytes) { size_t o = off; off = (off + bytes + 255) & ~(size_t)255; return o; };
  unsigned* bc1 = (unsigned*)(ws + take((size_t)NBAR * 16 * 16 * 4));
  unsigned* bc2 = (unsigned*)(ws + take((size_t)NBAR * 16 * 4));
  unsigned* gfl = (unsigned*)(ws + take((size_t)16 * 16 * 4));
  float* c0T  = (float*)(ws + take((size_t)2 * HB * 4));
  float* c1T  = (float*)(ws + take((size_t)HB * 4));
  float* c2T  = (float*)(ws + take((size_t)HB * 4));
  float* m0aT = (float*)(ws + take((size_t)HB * 4));
  float* m1aT = (float*)(ws + take((size_t)HB * 4));
  float* pacc = (float*)(ws + take((size_t)Tt * 2 * 1024 * 4));
  size_t zero_bytes = off;
  float* Wp  = (float*)(ws + take((size_t)NBLK * WPB * 4));
  float* GI0 = (float*)(ws + take((size_t)Tt * G3 * Bb * 4));
  if (ws_size < off) return;  // fail visibly rather than corrupt

  hipMemsetAsync(d_ws, 0, zero_bytes, stream);
  pack_weights<<<NBLK, 256, 0, stream>>>(Whh0, Wih, Whh, mW1, mW2, Wp);
  gi0_gemm<<<dim3(Tt / 4, G3 / 128), 256, 0, stream>>>(x, Wih0, bih0, GI0);
  hrnn_persist<<<NBLK, NTHR, 0, stream>>>(Wp, bhh0, bih, bhh, mb1, mb2, mW3, mb3, GI0,
      c0T, c1T, c2T, m0aT, m1aT, pacc, bc1, bc2, gfl, out);
}

// Round 7
// 58659.766 us; speedup vs baseline: 1.7575x; 1.7575x over previous
//
#include <hip/hip_runtime.h>
#include <math.h>

#define Tt 512
#define Dd 768
#define Hh 512
#define Bb 32
#define G3 1536
#define HB (Hh*Bb)
#define NBLK 256
#define NTHR 512
#define NBAR (Tt*4)
#define PR 32

__device__ __forceinline__ float sigf(float x) { return 1.f / (1.f + expf(-x)); }

__device__ __forceinline__ float dot4p(const float4 w4, const float* v) {
  return w4.x*v[0] + w4.y*v[1] + w4.z*v[2] + w4.w*v[3];
}

__device__ __forceinline__ void dstore(float* p, float v) {
  __hip_atomic_store(p, v, __ATOMIC_RELAXED, __HIP_MEMORY_SCOPE_AGENT);
}
__device__ __forceinline__ void dstore_u(unsigned* p, unsigned v) {
  __hip_atomic_store(p, v, __ATOMIC_RELAXED, __HIP_MEMORY_SCOPE_AGENT);
}
__device__ __forceinline__ unsigned dload_u(const unsigned* p) {
  return __hip_atomic_load(p, __ATOMIC_RELAXED, __HIP_MEMORY_SCOPE_AGENT);
}

// ---- barrier: EXACT Round-2-proven protocol (25.8ms / 734MB fetch anchor).
// two-level fetch_add arrive (16 groups x 16 blocks, 64B-strided counters),
// last arriver fans out to 16 replica release lines, ONE poller lane per block. ----
__device__ __forceinline__ void bar_arrive(unsigned* bc1, unsigned* bc2, unsigned* gfl, unsigned n)
{
  __syncthreads();   // drains vmcnt(0): all block stores at coherence point
  if (threadIdx.x == 0) {
    const unsigned idx = n - 1u;
    const unsigned grp = (unsigned)(blockIdx.x >> 4);
    unsigned old = __hip_atomic_fetch_add(&bc1[(idx * 16u + grp) * 16u], 1u,
                        __ATOMIC_RELAXED, __HIP_MEMORY_SCOPE_AGENT);
    if (old == 15u) {
      unsigned o2 = __hip_atomic_fetch_add(&bc2[idx * 16u], 1u,
                        __ATOMIC_RELAXED, __HIP_MEMORY_SCOPE_AGENT);
      if (o2 == 15u) {
#pragma unroll
        for (int g = 0; g < 16; ++g) dstore_u(&gfl[g * 16], n);
      }
    }
  }
}

__device__ __forceinline__ void bar_wait(unsigned* gfl, unsigned n)
{
  if (threadIdx.x == 0) {
    const unsigned grp = (unsigned)(blockIdx.x >> 4);
    while (dload_u(&gfl[grp * 16]) < n) __builtin_amdgcn_s_sleep(4);
  }
  __syncthreads();
}

__device__ __forceinline__ void grid_barrier(unsigned* bc1, unsigned* bc2, unsigned* gfl, unsigned n)
{
  bar_arrive(bc1, bc2, gfl, n);
  bar_wait(gfl, n);
}

// ---------------- GI0 = x @ Wih0^T + bih0, t-tiled by 4, layout [t][j][b] ----------------
__global__ __launch_bounds__(256) void gi0_gemm(const float* __restrict__ x,
                                                const float* __restrict__ Wih0,
                                                const float* __restrict__ bih0,
                                                float* __restrict__ GI0)
{
  const int t0 = blockIdx.x * 4;
  const int j0 = blockIdx.y * 128;
  const int tid = threadIdx.x;
  const int b = tid & 31, u = tid >> 5;   // u in [0,8)

  __shared__ float xs[4][64][33];
  float acc[16][4];
#pragma unroll
  for (int jj = 0; jj < 16; jj++)
#pragma unroll
    for (int tt = 0; tt < 4; tt++) acc[jj][tt] = 0.f;

  for (int kbv = 0; kbv < Dd; kbv += 64) {
    __syncthreads();
    {
      int r = tid >> 1, half = tid & 1;
      int tt = r >> 5, bb = r & 31;
      const float* xp = x + ((size_t)bb * Tt + t0 + tt) * Dd + kbv + half * 32;
#pragma unroll
      for (int q = 0; q < 8; q++) {
        float4 v = *(const float4*)(xp + q * 4);
        int k = half * 32 + q * 4;
        xs[tt][k + 0][bb] = v.x; xs[tt][k + 1][bb] = v.y;
        xs[tt][k + 2][bb] = v.z; xs[tt][k + 3][bb] = v.w;
      }
    }
    __syncthreads();
    for (int kk4 = 0; kk4 < 16; kk4++) {
      const int k = kk4 * 4;
      float xv[4][4];
#pragma unroll
      for (int tt = 0; tt < 4; tt++)
#pragma unroll
        for (int q = 0; q < 4; q++) xv[tt][q] = xs[tt][k + q][b];
#pragma unroll
      for (int jj = 0; jj < 16; jj++) {
        const float* wp = Wih0 + (size_t)(j0 + u + 8 * jj) * Dd + kbv + k;
        float4 w4 = *(const float4*)wp;
#pragma unroll
        for (int tt = 0; tt < 4; tt++)
          acc[jj][tt] += w4.x*xv[tt][0] + w4.y*xv[tt][1] + w4.z*xv[tt][2] + w4.w*xv[tt][3];
      }
    }
  }
#pragma unroll
  for (int jj = 0; jj < 16; jj++) {
    int j = j0 + u + 8 * jj;
    float bj = bih0[j];
#pragma unroll
    for (int tt = 0; tt < 4; tt++)
      GI0[((size_t)(t0 + tt) * G3 + j) * 32 + b] = acc[jj][tt] + bj;
  }
}

// ---------------- persistent HRNN kernel (Round-2-anchor memory scheme) ----------------
__global__ __launch_bounds__(NTHR, 1) void hrnn_persist(
    const float* __restrict__ Whh0, const float* __restrict__ bhh0,
    const float* __restrict__ Wih,  const float* __restrict__ Whh,
    const float* __restrict__ bih,  const float* __restrict__ bhh,
    const float* __restrict__ mW1,  const float* __restrict__ mb1,
    const float* __restrict__ mW2,  const float* __restrict__ mb2,
    const float* __restrict__ mW3,  const float* __restrict__ mb3,
    const float* __restrict__ GI0,
    float* __restrict__ c0R, float* __restrict__ c1R, float* __restrict__ c2R,
    float* __restrict__ m0aR, float* __restrict__ m1aR,
    float* __restrict__ pacc,
    unsigned* __restrict__ bc1, unsigned* __restrict__ bc2, unsigned* __restrict__ gfl,
    float* __restrict__ out)
{
  __shared__ float red[8][576];
  __shared__ float s_gh[12][32];
  __shared__ float s_pre[6][32];
  __shared__ float s_gi[6][32];
  __shared__ float s_ab[7][32];    // a0,a1,a2,w10,w11,p0,p1
  __shared__ float s_mb[2][32];
  __shared__ float s_g0[6][32];    // GI0 rows {i0,i0+1}+{0,512,1024}

  const int tid = threadIdx.x;
  const int b = tid & 31;
  const int u = tid >> 5;          // 0..15
  const int wv = tid >> 6;         // wave 0..7
  const int i0 = blockIdx.x * 2;
  const int kb = u * 32;
  const int grp = blockIdx.x >> 4;
  const float* Wih2 = Wih + (size_t)G3 * 512;
  const float* mW1b = mW1 + (size_t)512 * 512;
  const float* mW2b = mW2 + (size_t)512 * 512;

  for (int t = 0; t < Tt; t++) {
    const size_t wo = (size_t)(t & (PR - 1)) * HB;
    const size_t ro = (size_t)((t + PR - 1) & (PR - 1)) * HB;
    const float* c0o = c0R + ro;
    const float* c1o = c1R + ro;
    const float* c2o = c2R + ro;

    // ---- prefetch (issued BEFORE waiting on S4 arrivals of t-1) ----
    // c0o/c1o/c2o were written at S1/S2/S3 of t-1 -> barriers already passed by
    // this block. Same addresses the anchor kernel read post-wait; only earlier.
    float pf0[32], pf1[32], pf2[32];
#pragma unroll
    for (int q = 0; q < 32; q++) {
      int k = kb + q;
      pf0[q] = c0o[k * 32 + b];
      pf1[q] = c1o[k * 32 + b];
      pf2[q] = c2o[k * 32 + b];
    }
    float v0e = 0.f, v1e = 0.f, v2e = 0.f;
    int sie = 0;
    if (tid < 192) {
      int rw = tid >> 5, b2 = tid & 31;
      int j = (rw >> 1) * 512 + i0 + (rw & 1);
      s_g0[rw][b2] = GI0[((size_t)t * G3 + j) * 32 + b2];
    }
    if (tid < 64) {
      int ii = tid >> 5, bb = tid & 31;
      sie = (i0 + ii) * 32 + bb;
      v0e = c0o[sie]; v1e = c1o[sie]; v2e = c2o[sie];
    }

    // ---- wait for S4 arrivals of step t-1 ----
    if (t > 0) bar_wait(gfl, (unsigned)(4 * t));
    else __syncthreads();   // order s_g0 writes

    // ---- p-phase: p(t-1) from pacc partials; softmax mixing weights ----
    {
      const int pslot = (t + Tt - 1) & (Tt - 1);
      if (tid < 64) {
        int which = tid >> 5, b2 = tid & 31;
        const float* pp = pacc + ((size_t)pslot * 2 + which) * 512;
        float s = mb3[which];
#pragma unroll
        for (int g = 0; g < 16; g++) s += pp[g * 32 + b2];
        s_ab[5 + which][b2] = sigf(s);
      }
      __syncthreads();
      if (tid < 32) {
        float p0 = s_ab[5][tid], p1 = s_ab[6][tid];
        float e0 = expf(1.f - p0), e1 = expf(p0 * (1.f - p1)), e2 = expf(p0 * p1);
        float inv = 1.f / (e0 + e1 + e2);
        s_ab[0][tid] = e0 * inv; s_ab[1][tid] = e1 * inv; s_ab[2][tid] = e2 * inv;
        float q0 = expf(1.f - p1), q1 = expf(p1);
        float qi = 1.f / (q0 + q1);
        s_ab[3][tid] = q0 * qi; s_ab[4][tid] = q1 * qi;
        if (t > 0 && blockIdx.x == 0) {
          out[((size_t)tid * Tt + (t - 1)) * 2 + 0] = p0;
          out[((size_t)tid * Tt + (t - 1)) * 2 + 1] = p1;
        }
      }
      __syncthreads();
    }

    const float a0 = s_ab[0][b], a1 = s_ab[1][b], a2 = s_ab[2][b];
    const float w10 = s_ab[3][b], w11 = s_ab[4][b];

    // ---- S1: gh0/gh1/gh2 with inline h-mixing; cell0 ----
    {
      float acc[18];
#pragma unroll
      for (int w = 0; w < 18; w++) acc[w] = 0.f;
#pragma unroll
      for (int kk = 0; kk < 32; kk += 4) {
        float mh0[4], mh1[4], vv2[4];
#pragma unroll
        for (int q = 0; q < 4; q++) {
          float v0 = pf0[kk + q], v1 = pf1[kk + q], v2 = pf2[kk + q];
          vv2[q] = v2;
          mh0[q] = a0 * v0 + a1 * v1 + a2 * v2;
          mh1[q] = w10 * v1 + w11 * v2;
        }
#pragma unroll
        for (int w = 0; w < 18; w++) {
          const int l = w / 6, rem = w % 6, g = rem >> 1, ii = rem & 1;
          const int row = g * 512 + i0 + ii;
          const float* wp = (l == 0) ? (Whh0 + (size_t)row * 512)
                                     : (Whh + ((size_t)(l - 1) * G3 + row) * 512);
          float4 w4 = *(const float4*)(wp + kb + kk);
          const float* mv = (l == 0) ? mh0 : (l == 1) ? mh1 : vv2;
          acc[w] += dot4p(w4, mv);
        }
      }
#pragma unroll
      for (int w = 0; w < 18; w++) acc[w] += __shfl_xor(acc[w], 32, 64);
      if ((tid & 63) < 32) {
#pragma unroll
        for (int w = 0; w < 18; w++) red[wv][w * 32 + b] = acc[w];
      }
      __syncthreads();
      for (int o = tid; o < 18 * 32; o += NTHR) {
        float s = 0.f;
#pragma unroll
        for (int q = 0; q < 8; q++) s += red[q][o];
        int w = o >> 5, b2 = o & 31;
        int l = w / 6, rem = w % 6, g = rem >> 1, ii = rem & 1;
        int row = g * 512 + i0 + ii;
        if (l == 0) {
          s += bhh0[row];
          if (g < 2) s += s_g0[rem][b2];
          s_pre[rem][b2] = s;
        } else if (l == 1) {
          s_gh[rem][b2] = s + bhh[row];
        } else {
          s_gh[6 + rem][b2] = s + bhh[G3 + row];
        }
      }
      __syncthreads();
      if (tid < 64) {
        int ii = tid >> 5, bb = tid & 31;
        float r = sigf(s_pre[ii][bb]);
        float z = sigf(s_pre[2 + ii][bb]);
        float n = tanhf(s_g0[4 + ii][bb] + r * s_pre[4 + ii][bb]);
        float h0old = s_ab[0][bb] * v0e + s_ab[1][bb] * v1e + s_ab[2][bb] * v2e;
        dstore(&c0R[wo + sie], (1.f - z) * n + z * h0old);
      }
    }
    grid_barrier(bc1, bc2, gfl, (unsigned)(4 * t + 1));

    // ---- S2: gi1 (over cell0) + m0a; cell1 ----
    {
      const float* c0n = c0R + wo;
      float acc[8];
#pragma unroll
      for (int w = 0; w < 8; w++) acc[w] = 0.f;
      for (int kk = 0; kk < 32; kk += 4) {
        float v[4];
#pragma unroll
        for (int q = 0; q < 4; q++) v[q] = c0n[(kb + kk + q) * 32 + b];
#pragma unroll
        for (int w = 0; w < 8; w++) {
          const float* wp = (w < 6) ? (Wih + (size_t)((w >> 1) * 512 + i0 + (w & 1)) * 512)
                                    : (mW1 + (size_t)(i0 + (w - 6)) * 512);
          float4 w4 = *(const float4*)(wp + kb + kk);
          acc[w] += dot4p(w4, v);
        }
      }
#pragma unroll
      for (int w = 0; w < 8; w++) acc[w] += __shfl_xor(acc[w], 32, 64);
      if ((tid & 63) < 32) {
#pragma unroll
        for (int w = 0; w < 8; w++) red[wv][w * 32 + b] = acc[w];
      }
      __syncthreads();
      if (tid < 8 * 32) {
        float s = 0.f;
#pragma unroll
        for (int q = 0; q < 8; q++) s += red[q][tid];
        int w = tid >> 5, b2 = tid & 31;
        if (w < 6) {
          int row = (w >> 1) * 512 + i0 + (w & 1);
          s_gi[w][b2] = s + bih[row];
        } else {
          int col = i0 + (w - 6);
          dstore(&m0aR[wo + col * 32 + b2], fmaxf(s + mb1[col], 0.f));
        }
      }
      __syncthreads();
      if (tid < 64) {
        int ii = tid >> 5, bb = tid & 31;
        float r = sigf(s_gi[ii][bb] + s_gh[ii][bb]);
        float z = sigf(s_gi[2 + ii][bb] + s_gh[2 + ii][bb]);
        float n = tanhf(s_gi[4 + ii][bb] + r * s_gh[4 + ii][bb]);
        float h1old = s_ab[3][bb] * v1e + s_ab[4][bb] * v2e;
        dstore(&c1R[wo + sie], (1.f - z) * n + z * h1old);
      }
    }
    grid_barrier(bc1, bc2, gfl, (unsigned)(4 * t + 2));

    // ---- S3: gi2 + m0b + m1a; cell2; p0 partials ----
    {
      const float* c1n = c1R + wo;
      const float* m0a = m0aR + wo;
      float acc[10];
#pragma unroll
      for (int w = 0; w < 10; w++) acc[w] = 0.f;
      for (int kk = 0; kk < 32; kk += 4) {
        float v[4], vm[4];
#pragma unroll
        for (int q = 0; q < 4; q++) {
          v[q]  = c1n[(kb + kk + q) * 32 + b];
          vm[q] = m0a[(kb + kk + q) * 32 + b];
        }
#pragma unroll
        for (int w = 0; w < 10; w++) {
          const float* wp = (w < 6) ? (Wih2 + (size_t)((w >> 1) * 512 + i0 + (w & 1)) * 512)
                          : (w < 8) ? (mW2 + (size_t)(i0 + (w - 6)) * 512)
                                    : (mW1b + (size_t)(i0 + (w - 8)) * 512);
          float4 w4 = *(const float4*)(wp + kb + kk);
          acc[w] += dot4p(w4, (w < 6 || w >= 8) ? v : vm);
        }
      }
#pragma unroll
      for (int w = 0; w < 10; w++) acc[w] += __shfl_xor(acc[w], 32, 64);
      if ((tid & 63) < 32) {
#pragma unroll
        for (int w = 0; w < 10; w++) red[wv][w * 32 + b] = acc[w];
      }
      __syncthreads();
      if (tid < 10 * 32) {
        float s = 0.f;
#pragma unroll
        for (int q = 0; q < 8; q++) s += red[q][tid];
        int w = tid >> 5, b2 = tid & 31;
        if (w < 6) {
          int row = (w >> 1) * 512 + i0 + (w & 1);
          s_gi[w][b2] = s + bih[G3 + row];
        } else if (w < 8) {
          s_mb[w - 6][b2] = fmaxf(s + mb2[i0 + (w - 6)], 0.f);
        } else {
          int col = i0 + (w - 8);
          dstore(&m1aR[wo + col * 32 + b2], fmaxf(s + mb1[512 + col], 0.f));
        }
      }
      __syncthreads();
      if (tid < 64) {
        int ii = tid >> 5, bb = tid & 31;
        float r = sigf(s_gi[ii][bb] + s_gh[6 + ii][bb]);
        float z = sigf(s_gi[2 + ii][bb] + s_gh[8 + ii][bb]);
        float n = tanhf(s_gi[4 + ii][bb] + r * s_gh[10 + ii][bb]);
        dstore(&c2R[wo + sie], (1.f - z) * n + z * v2e);
      } else if (tid < 96) {
        int b2 = tid - 64;
        float part = mW3[i0] * s_mb[0][b2] + mW3[i0 + 1] * s_mb[1][b2];
        __hip_atomic_fetch_add(&pacc[((size_t)t * 2 + 0) * 512 + grp * 32 + b2], part,
                               __ATOMIC_RELAXED, __HIP_MEMORY_SCOPE_AGENT);
      }
    }
    grid_barrier(bc1, bc2, gfl, (unsigned)(4 * t + 3));

    // ---- S4: m1b + p1 partials; arrive-only (wait folded into next p-phase) ----
    {
      const float* m1a = m1aR + wo;
      float acc2[2] = {0.f, 0.f};
      for (int kk = 0; kk < 32; kk += 4) {
        float vm[4];
#pragma unroll
        for (int q = 0; q < 4; q++) vm[q] = m1a[(kb + kk + q) * 32 + b];
#pragma unroll
        for (int w = 0; w < 2; w++) {
          const float* wp = mW2b + (size_t)(i0 + w) * 512;
          float4 w4 = *(const float4*)(wp + kb + kk);
          acc2[w] += dot4p(w4, vm);
        }
      }
#pragma unroll
      for (int w = 0; w < 2; w++) acc2[w] += __shfl_xor(acc2[w], 32, 64);
      if ((tid & 63) < 32) {
        red[wv][b] = acc2[0]; red[wv][32 + b] = acc2[1];
      }
      __syncthreads();
      if (tid < 64) {
        float s = 0.f;
#pragma unroll
        for (int q = 0; q < 8; q++) s += red[q][tid];
        int w = tid >> 5, b2 = tid & 31;
        s_mb[w][b2] = fmaxf(s + mb2[512 + i0 + w], 0.f);
      }
      __syncthreads();
      if (tid >= 64 && tid < 96) {
        int b2 = tid - 64;
        float part = mW3[512 + i0] * s_mb[0][b2] + mW3[512 + i0 + 1] * s_mb[1][b2];
        __hip_atomic_fetch_add(&pacc[((size_t)t * 2 + 1) * 512 + grp * 32 + b2], part,
                               __ATOMIC_RELAXED, __HIP_MEMORY_SCOPE_AGENT);
      }
    }
    bar_arrive(bc1, bc2, gfl, (unsigned)(4 * t + 4));
  }

  // ---- final output column t = T-1 (block 0 waits for last S4) ----
  if (blockIdx.x == 0) {
    bar_wait(gfl, (unsigned)(4 * Tt));
    if (tid < 64) {
      int which = tid >> 5, b2 = tid & 31;
      const float* pp = pacc + ((size_t)(Tt - 1) * 2 + which) * 512;
      float s = mb3[which];
#pragma unroll
      for (int g = 0; g < 16; g++) s += pp[g * 32 + b2];
      out[((size_t)b2 * Tt + (Tt - 1)) * 2 + which] = sigf(s);
    }
  }
}

extern "C" void kernel_launch(void* const* d_in, const int* in_sizes, int n_in,
                              void* d_out, int out_size, void* d_ws, size_t ws_size,
                              hipStream_t stream)
{
  (void)in_sizes; (void)n_in; (void)out_size;
  const float* x    = (const float*)d_in[0];
  const float* Wih0 = (const float*)d_in[1];
  const float* Whh0 = (const float*)d_in[2];
  const float* bih0 = (const float*)d_in[3];
  const float* bhh0 = (const float*)d_in[4];
  const float* Wih  = (const float*)d_in[5];
  const float* Whh  = (const float*)d_in[6];
  const float* bih  = (const float*)d_in[7];
  const float* bhh  = (const float*)d_in[8];
  const float* mW1  = (const float*)d_in[9];
  const float* mb1  = (const float*)d_in[10];
  const float* mW2  = (const float*)d_in[11];
  const float* mb2  = (const float*)d_in[12];
  const float* mW3  = (const float*)d_in[13];
  const float* mb3  = (const float*)d_in[14];
  float* out = (float*)d_out;

  char* ws = (char*)d_ws;
  size_t off = 0;
  auto take = [&](size_t bytes) { size_t o = off; off = (off + bytes + 255) & ~(size_t)255; return o; };
  unsigned* bc1 = (unsigned*)(ws + take((size_t)NBAR * 16 * 16 * 4));
  unsigned* bc2 = (unsigned*)(ws + take((size_t)NBAR * 16 * 4));
  unsigned* gfl = (unsigned*)(ws + take((size_t)16 * 16 * 4));
  float* c0R  = (float*)(ws + take((size_t)PR * HB * 4));
  float* c1R  = (float*)(ws + take((size_t)PR * HB * 4));
  float* c2R  = (float*)(ws + take((size_t)PR * HB * 4));
  float* m0aR = (float*)(ws + take((size_t)PR * HB * 4));
  float* m1aR = (float*)(ws + take((size_t)PR * HB * 4));
  float* pacc = (float*)(ws + take((size_t)Tt * 2 * 512 * 4));
  size_t zero_bytes = off;
  float* GI0 = (float*)(ws + take((size_t)Tt * G3 * Bb * 4));
  if (ws_size < off) return;  // fail visibly rather than corrupt

  hipMemsetAsync(d_ws, 0, zero_bytes, stream);
  gi0_gemm<<<dim3(Tt / 4, G3 / 128), 256, 0, stream>>>(x, Wih0, bih0, GI0);
  hrnn_persist<<<NBLK, NTHR, 0, stream>>>(Whh0, bhh0, Wih, Whh, bih, bhh,
      mW1, mb1, mW2, mb2, mW3, mb3, GI0,
      c0R, c1R, c2R, m0aR, m1aR, pacc, bc1, bc2, gfl, out);
}